// Round 3
// baseline (682.668 us; speedup 1.0000x reference)
//
#include <hip/hip_runtime.h>
#include <hip/hip_bf16.h>

// ModulatedConv2d: out = demod[b,co] * ( (conv_scale*weight) ⊛ (x * s[b,ci]) ), plus s5 output.
// Shared-filter implicit GEMM, bf16 MFMA 16x16x32, fp32 acc.
// R3: wave tile 128co x 64pos (mf=8) halves LDS-reads/MFMA (LDS pipe was the limiter);
//     div-free staging; XCD-chunk swizzle pins one batch image per XCD L2.

typedef __attribute__((ext_vector_type(8))) short short8;
typedef __attribute__((ext_vector_type(4))) float f32x4;

#define LIN_SCALE 0.04419417382415922f     /* 1/sqrt(512) */
#define CONV_SCALE 0.014731391274719739f   /* 1/sqrt(4608) */
#define CONV_SCALE2 (1.0f/4608.0f)
#define OUT_IMG (8*512*64*64)

static __device__ __forceinline__ unsigned short f2bf(float f) {
    union { float f; unsigned int u; } a; a.f = f;
    unsigned int u = a.u;
    return (unsigned short)((u + 0x7fffu + ((u >> 16) & 1u)) >> 16); // RNE
}
static __device__ __forceinline__ short8 as_s8(uint4 v) {
    union { uint4 u; short8 s; } x; x.u = v; return x.s;
}

// ---------------- kernel 1: s[b,ci] = style @ (mod_weight*lin_scale)^T + bias; also s5 out ----
__global__ __launch_bounds__(256) void k_style(const float* __restrict__ style,
                                               const float* __restrict__ mw,
                                               const float* __restrict__ mb,
                                               float* __restrict__ s_ws,
                                               float* __restrict__ out_s5) {
    int wid = blockIdx.x * 4 + (threadIdx.x >> 6);   // 4096 waves: one per (b,ci)
    int lane = threadIdx.x & 63;
    int b = wid >> 9, ci = wid & 511;
    float sum = 0.f;
    for (int k = lane; k < 512; k += 64)
        sum += style[b*512 + k] * mw[ci*512 + k];
    for (int off = 32; off > 0; off >>= 1) sum += __shfl_xor(sum, off);
    if (lane == 0) {
        float v = sum * LIN_SCALE + mb[ci];
        s_ws[b*512 + ci] = v;
        out_s5[b*512 + ci] = v;   // s5 flat = (B,1,Cin,1,1)
    }
}

// ------- kernel 2b: wfrag in MFMA A-fragment order: [t][cig(16)][cog(32)][lane(64)] x uint4 ---
// lane l holds 8 bf16: w[co = cog*16 + (l&15)][ci = cig*32 + (l>>4)*8 + j][t] * conv_scale
__global__ __launch_bounds__(256) void k_wprep(const float* __restrict__ weight,
                                               unsigned short* __restrict__ wfrag) {
    __shared__ float wsh[4608];
    int co = blockIdx.x;
    int cog = co >> 4, l15 = co & 15;
    for (int i = threadIdx.x; i < 4608; i += 256) wsh[i] = weight[co*4608 + i];
    __syncthreads();
    uint4* wf4 = (uint4*)wfrag;
    for (int idx = threadIdx.x; idx < 576; idx += 256) {   // 9 t x 16 cig x 4 lg
        int t = idx / 64;
        int rem = idx & 63;
        int cig = rem >> 2, lg = rem & 3;
        union { unsigned short h[8]; uint4 v; } u;
        #pragma unroll
        for (int j = 0; j < 8; ++j)
            u.h[j] = f2bf(wsh[(cig*32 + lg*8 + j)*9 + t] * CONV_SCALE);
        wf4[((t*16 + cig)*32 + cog)*64 + lg*16 + l15] = u.v;
    }
}

// ---------------- kernel 2: demod[b][co] = rsqrt(conv_scale^2 * sum((w*s)^2) + eps) ----------
__global__ __launch_bounds__(256) void k_demod(const float* __restrict__ weight,
                                               const float* __restrict__ s_ws,
                                               float* __restrict__ demod) {
    __shared__ float s2[4096];
    __shared__ float red[4][8];
    int co = blockIdx.x;
    for (int i = threadIdx.x; i < 4096; i += 256) { float v = s_ws[i]; s2[i] = v*v; }
    __syncthreads();
    float acc[8] = {0,0,0,0,0,0,0,0};
    for (int idx = threadIdx.x; idx < 4608; idx += 256) {
        float w = weight[co*4608 + idx];
        float w2 = w*w;
        int ci = idx / 9;
        #pragma unroll
        for (int b = 0; b < 8; ++b) acc[b] += w2 * s2[b*512 + ci];
    }
    int lane = threadIdx.x & 63, wv = threadIdx.x >> 6;
    #pragma unroll
    for (int b = 0; b < 8; ++b) {
        float v = acc[b];
        for (int off = 32; off > 0; off >>= 1) v += __shfl_xor(v, off);
        if (lane == 0) red[wv][b] = v;
    }
    __syncthreads();
    if (threadIdx.x < 8) {
        float t = red[0][threadIdx.x] + red[1][threadIdx.x]
                + red[2][threadIdx.x] + red[3][threadIdx.x];
        demod[threadIdx.x*512 + co] = rsqrtf(t * CONV_SCALE2 + 1e-8f);
    }
}

// ---------------- kernel 3: xs[b][h][w][ci] = bf16(x[b][ci][h][w] * s[b][ci])  (NHWC) --------
__global__ __launch_bounds__(256) void k_xprep(const float* __restrict__ x,
                                               const float* __restrict__ s_ws,
                                               unsigned short* __restrict__ xs) {
    __shared__ unsigned short tile[32 * 520];        // 32 w-rows x 512 ci, stride 520
    int w0 = blockIdx.x * 32, h = blockIdx.y, b = blockIdx.z;
    int t = threadIdx.x;
    int wl = t & 31, cih = t >> 5;                    // 32 w x 8 ci per iter
    for (int ci0 = 0; ci0 < 512; ci0 += 8) {
        int ci = ci0 + cih;
        float sv = s_ws[b*512 + ci];
        float v = x[((b*512 + ci)*64 + h)*64 + (w0 + wl)] * sv;   // coalesced over w
        tile[wl*520 + ci] = f2bf(v);
    }
    __syncthreads();
    int lane = t & 63, wv = t >> 6;
    const uint4* t4 = (const uint4*)tile;             // 65 uint4 per row
    uint4* xs4 = (uint4*)xs;
    for (int w = wv; w < 32; w += 4) {
        uint4 v = t4[w*65 + lane];
        xs4[((b*64 + h)*64 + (w0 + w))*64 + lane] = v;  // coalesced 1KB row store
    }
}

// ---------------- kernel 4: implicit-GEMM conv, epilogue demod scale -------------------------
// Block: 256 co x (2 rows x 64 cols), 4 waves (wm: co-half, wn: row). Wave tile 128co x 64pos:
// mf=8, nf=4 -> LDS reads per MFMA halved vs R2 (LDS pipe was the limiter).
// LDS x tile: [4 rows][4 ci-grps][66 cols][8 ci] bf16 = 16.9KB, double buffered.
// Grid: 512 blocks 1D with XCD-chunk swizzle -> 64 blocks (= one batch image) per XCD.
__global__ __launch_bounds__(256, 2) void k_conv(const unsigned short* __restrict__ xs,
                                                 const unsigned short* __restrict__ wfrag,
                                                 const float* __restrict__ demod,
                                                 float* __restrict__ out) {
    __shared__ uint4 lds[2][1056];                    // 2 x 16.9KB
    int orig = ((blockIdx.x & 7) << 6) + (blockIdx.x >> 3);  // XCD k gets blocks [64k,64k+64)
    int b   = orig >> 6;
    int rem = orig & 63;
    int r0  = (rem >> 1) * 2;                         // row-tile (0..31) * 2
    int cot = rem & 1;                                // co half (256 co each)
    int tid = threadIdx.x;
    int lane = tid & 63, wid = tid >> 6;
    int wm = wid & 1, wn = wid >> 1;
    int l15 = lane & 15, lg = lane >> 4;
    int cobase = cot*256 + wm*128;
    int cog0 = cobase >> 4;                           // base co-group (16-co units)

    const uint4* xs4 = (const uint4*)xs;
    const uint4* wf4 = (const uint4*)wfrag;

    f32x4 acc[8][4];
    #pragma unroll
    for (int i = 0; i < 8; ++i)
        #pragma unroll
        for (int j = 0; j < 4; ++j) acc[i][j] = (f32x4){0.f,0.f,0.f,0.f};

    // div-free staging: 1056 = 4 rows x 4 grps x 66 cols (16B each), 256 threads, 5 passes
    int sg = tid & 3;                                 // ci-grp
    int sc0 = tid >> 2;                               // start col (0..63), row 0
    auto stage = [&](int p, int cq) {
        int c = sc0, r = 0;
        #pragma unroll
        for (int k = 0; k < 5; ++k) {
            if (k < 4 || tid < 32) {
                int rin = r0 - 1 + r;
                int cin = c - 1;
                uint4 v = {0u,0u,0u,0u};
                if (((unsigned)rin < 64u) && ((unsigned)cin < 64u))
                    v = xs4[((b*64 + rin)*64 + cin)*64 + cq + sg];
                lds[p][(r*4 + sg)*66 + c] = v;
            }
            c += 64;
            if (c >= 66) { c -= 66; ++r; }
        }
    };

    stage(0, 0);
    __syncthreads();

    #pragma unroll 1
    for (int step = 0; step < 16; ++step) {            // K over ci, BK=32 (cig == step)
        int p = step & 1;
        if (step < 15) stage(p ^ 1, (step+1) * 4);     // prefetch next ci-tile
        #pragma unroll
        for (int kh = 0; kh < 3; ++kh) {
            int rt = wn + kh;                           // row within 4-row tile
            #pragma unroll
            for (int kw = 0; kw < 3; ++kw) {
                int t = kh*3 + kw;
                short8 a[8], bx[4];
                #pragma unroll
                for (int mf = 0; mf < 8; ++mf)          // A: coalesced 1KB fragment reads (L2)
                    a[mf] = as_s8(wf4[((t*16 + step)*32 + cog0 + mf)*64 + lane]);
                #pragma unroll
                for (int nf = 0; nf < 4; ++nf) {        // B: x frags, single ds_read_b128 each
                    int slot = (rt*4 + lg)*66 + nf*16 + kw + l15;
                    bx[nf] = as_s8(lds[p][slot]);
                }
                #pragma unroll
                for (int mf = 0; mf < 8; ++mf)
                    #pragma unroll
                    for (int nf = 0; nf < 4; ++nf)
                        acc[mf][nf] = __builtin_amdgcn_mfma_f32_16x16x32_bf16(
                            a[mf], bx[nf], acc[mf][nf], 0, 0, 0);
            }
        }
        __syncthreads();
    }

    // epilogue: scale by demod[b][co], write NCHW f32
    int r = r0 + wn;
    const float* dmp = demod + b*512;
    #pragma unroll
    for (int mf = 0; mf < 8; ++mf) {
        #pragma unroll
        for (int reg = 0; reg < 4; ++reg) {
            int co = cobase + mf*16 + lg*4 + reg;       // C/D: row=(lane>>4)*4+reg
            float dm = dmp[co];
            #pragma unroll
            for (int nf = 0; nf < 4; ++nf) {
                int c = nf*16 + l15;                    // C/D: col=lane&15
                out[((b*512 + co)*64 + r)*64 + c] = acc[mf][nf][reg] * dm;
            }
        }
    }
}

extern "C" void kernel_launch(void* const* d_in, const int* in_sizes, int n_in,
                              void* d_out, int out_size, void* d_ws, size_t ws_size,
                              hipStream_t stream) {
    const float* x      = (const float*)d_in[0];
    const float* style  = (const float*)d_in[1];
    const float* weight = (const float*)d_in[2];
    const float* mw     = (const float*)d_in[3];
    const float* mb     = (const float*)d_in[4];
    float* out = (float*)d_out;

    // workspace layout (38.3MB total):
    float* s_ws           = (float*)d_ws;                                  // 16KB
    float* demod_ws       = (float*)((char*)d_ws + 16384);                 // 16KB
    unsigned short* wfrag = (unsigned short*)((char*)d_ws + 32768);        // 4.5MB  [9][16][32][64][8] bf16
    unsigned short* xs    = (unsigned short*)((char*)d_ws + 4751360);      // 32MB   [8][64][64][512] bf16

    k_style<<<1024, 256, 0, stream>>>(style, mw, mb, s_ws, out + OUT_IMG);
    k_wprep<<<512, 256, 0, stream>>>(weight, wfrag);
    k_demod<<<512, 256, 0, stream>>>(weight, s_ws, demod_ws);
    k_xprep<<<dim3(2, 64, 8), 256, 0, stream>>>(x, s_ws, xs);
    k_conv<<<512, 256, 0, stream>>>(xs, wfrag, demod_ws, out);
}

// Round 4
// 353.636 us; speedup vs baseline: 1.9304x; 1.9304x over previous
//
#include <hip/hip_runtime.h>
#include <hip/hip_bf16.h>

// ModulatedConv2d: out = demod[b,co] * ( (conv_scale*weight) ⊛ (x * s[b,ci]) ), plus s5 output.
// Shared-filter implicit GEMM, bf16 MFMA 16x16x32, fp32 acc.
// R4: back to R2 tile (64x64 wave, mf=4, 1024 blocks, natural order). Single 16.9KB LDS buffer
//     (4 blocks/CU instead of 2) + T14 reg-staged issue-early/write-late pipeline.
//     Halo cols are structurally zero -> pre-zeroed once, staging is exactly 4 items/thread.

typedef __attribute__((ext_vector_type(8))) short short8;
typedef __attribute__((ext_vector_type(4))) float f32x4;

#define LIN_SCALE 0.04419417382415922f     /* 1/sqrt(512) */
#define CONV_SCALE 0.014731391274719739f   /* 1/sqrt(4608) */
#define CONV_SCALE2 (1.0f/4608.0f)
#define OUT_IMG (8*512*64*64)

static __device__ __forceinline__ unsigned short f2bf(float f) {
    union { float f; unsigned int u; } a; a.f = f;
    unsigned int u = a.u;
    return (unsigned short)((u + 0x7fffu + ((u >> 16) & 1u)) >> 16); // RNE
}
static __device__ __forceinline__ short8 as_s8(uint4 v) {
    union { uint4 u; short8 s; } x; x.u = v; return x.s;
}

// ---------------- kernel 1: s[b,ci] = style @ (mod_weight*lin_scale)^T + bias; also s5 out ----
__global__ __launch_bounds__(256) void k_style(const float* __restrict__ style,
                                               const float* __restrict__ mw,
                                               const float* __restrict__ mb,
                                               float* __restrict__ s_ws,
                                               float* __restrict__ out_s5) {
    int wid = blockIdx.x * 4 + (threadIdx.x >> 6);   // 4096 waves: one per (b,ci)
    int lane = threadIdx.x & 63;
    int b = wid >> 9, ci = wid & 511;
    float sum = 0.f;
    for (int k = lane; k < 512; k += 64)
        sum += style[b*512 + k] * mw[ci*512 + k];
    for (int off = 32; off > 0; off >>= 1) sum += __shfl_xor(sum, off);
    if (lane == 0) {
        float v = sum * LIN_SCALE + mb[ci];
        s_ws[b*512 + ci] = v;
        out_s5[b*512 + ci] = v;   // s5 flat = (B,1,Cin,1,1)
    }
}

// ------- kernel 2b: wfrag in MFMA A-fragment order: [t][cig(16)][cog(32)][lane(64)] x uint4 ---
// lane l holds 8 bf16: w[co = cog*16 + (l&15)][ci = cig*32 + (l>>4)*8 + j][t] * conv_scale
__global__ __launch_bounds__(256) void k_wprep(const float* __restrict__ weight,
                                               unsigned short* __restrict__ wfrag) {
    __shared__ float wsh[4608];
    int co = blockIdx.x;
    int cog = co >> 4, l15 = co & 15;
    for (int i = threadIdx.x; i < 4608; i += 256) wsh[i] = weight[co*4608 + i];
    __syncthreads();
    uint4* wf4 = (uint4*)wfrag;
    for (int idx = threadIdx.x; idx < 576; idx += 256) {   // 9 t x 16 cig x 4 lg
        int t = idx / 64;
        int rem = idx & 63;
        int cig = rem >> 2, lg = rem & 3;
        union { unsigned short h[8]; uint4 v; } u;
        #pragma unroll
        for (int j = 0; j < 8; ++j)
            u.h[j] = f2bf(wsh[(cig*32 + lg*8 + j)*9 + t] * CONV_SCALE);
        wf4[((t*16 + cig)*32 + cog)*64 + lg*16 + l15] = u.v;
    }
}

// ---------------- kernel 2: demod[b][co] = rsqrt(conv_scale^2 * sum((w*s)^2) + eps) ----------
__global__ __launch_bounds__(256) void k_demod(const float* __restrict__ weight,
                                               const float* __restrict__ s_ws,
                                               float* __restrict__ demod) {
    __shared__ float s2[4096];
    __shared__ float red[4][8];
    int co = blockIdx.x;
    for (int i = threadIdx.x; i < 4096; i += 256) { float v = s_ws[i]; s2[i] = v*v; }
    __syncthreads();
    float acc[8] = {0,0,0,0,0,0,0,0};
    for (int idx = threadIdx.x; idx < 4608; idx += 256) {
        float w = weight[co*4608 + idx];
        float w2 = w*w;
        int ci = idx / 9;
        #pragma unroll
        for (int b = 0; b < 8; ++b) acc[b] += w2 * s2[b*512 + ci];
    }
    int lane = threadIdx.x & 63, wv = threadIdx.x >> 6;
    #pragma unroll
    for (int b = 0; b < 8; ++b) {
        float v = acc[b];
        for (int off = 32; off > 0; off >>= 1) v += __shfl_xor(v, off);
        if (lane == 0) red[wv][b] = v;
    }
    __syncthreads();
    if (threadIdx.x < 8) {
        float t = red[0][threadIdx.x] + red[1][threadIdx.x]
                + red[2][threadIdx.x] + red[3][threadIdx.x];
        demod[threadIdx.x*512 + co] = rsqrtf(t * CONV_SCALE2 + 1e-8f);
    }
}

// ---------------- kernel 3: xs[b][h][w][ci] = bf16(x[b][ci][h][w] * s[b][ci])  (NHWC) --------
__global__ __launch_bounds__(256) void k_xprep(const float* __restrict__ x,
                                               const float* __restrict__ s_ws,
                                               unsigned short* __restrict__ xs) {
    __shared__ unsigned short tile[32 * 520];        // 32 w-rows x 512 ci, stride 520
    int w0 = blockIdx.x * 32, h = blockIdx.y, b = blockIdx.z;
    int t = threadIdx.x;
    int wl = t & 31, cih = t >> 5;                    // 32 w x 8 ci per iter
    for (int ci0 = 0; ci0 < 512; ci0 += 8) {
        int ci = ci0 + cih;
        float sv = s_ws[b*512 + ci];
        float v = x[((b*512 + ci)*64 + h)*64 + (w0 + wl)] * sv;   // coalesced over w
        tile[wl*520 + ci] = f2bf(v);
    }
    __syncthreads();
    int lane = t & 63, wv = t >> 6;
    const uint4* t4 = (const uint4*)tile;             // 65 uint4 per row
    uint4* xs4 = (uint4*)xs;
    for (int w = wv; w < 32; w += 4) {
        uint4 v = t4[w*65 + lane];
        xs4[((b*64 + h)*64 + (w0 + w))*64 + lane] = v;  // coalesced 1KB row store
    }
}

// ---------------- kernel 4: implicit-GEMM conv, epilogue demod scale -------------------------
// Block: 128 co x (2 rows x 64 cols). 4 waves 2x2; wave tile 64co x 64pos (mf=4, nf=4).
// Single LDS x-tile [4 rows][4 ci-grps][66 cols][8ci] = 16.9KB; T14 pipeline:
//   loop: barrier; ds_write st (prev issue); barrier; issue next loads; compute 9 taps.
__global__ __launch_bounds__(256, 4) void k_conv(const unsigned short* __restrict__ xs,
                                                 const unsigned short* __restrict__ wfrag,
                                                 const float* __restrict__ demod,
                                                 float* __restrict__ out) {
    __shared__ uint4 lds[1056];                       // [r*4+g][66] uint4
    int cot = blockIdx.x;                             // 0..3  -> co0 = 128*cot
    int r0  = blockIdx.y * 2;                         // 0..62
    int b   = blockIdx.z;
    int tid = threadIdx.x;
    int lane = tid & 63, wid = tid >> 6;
    int wm = wid & 1, wn = wid >> 1;
    int l15 = lane & 15, lg = lane >> 4;
    int cobase = cot*128 + wm*64;
    int cog0 = cobase >> 4;                           // base co-group (16-co units)

    const uint4* xs4 = (const uint4*)xs;
    const uint4* wf4 = (const uint4*)wfrag;

    f32x4 acc[4][4];
    #pragma unroll
    for (int i = 0; i < 4; ++i)
        #pragma unroll
        for (int j = 0; j < 4; ++j) acc[i][j] = (f32x4){0.f,0.f,0.f,0.f};

    // staging: interior cols only (c=1..64), 4 rows x 4 grps x 64 cols = 1024 = 4/thread
    int sg  = tid & 3;                                // ci-grp
    int sc  = 1 + (tid >> 2);                         // tile col 1..64
    int scm1 = tid >> 2;                              // spatial col 0..63
    const uint4* xrow = xs4 + ((b*64 + (r0 - 1))*64 + scm1)*64 + sg;  // row k adds k*4096

    uint4 st[4];
    auto issue = [&](int cq) {
        #pragma unroll
        for (int k = 0; k < 4; ++k) {
            int rin = r0 - 1 + k;
            st[k] = (uint4){0u,0u,0u,0u};
            if ((unsigned)rin < 64u) st[k] = xrow[k*4096 + cq];
        }
    };

    // halo cols c=0 and c=65 are structurally zero (W padding) for every step: zero once.
    if (tid < 32) {
        int q = tid & 15;                              // r*4+g
        int col = (tid >> 4) ? 65 : 0;
        lds[q*66 + col] = (uint4){0u,0u,0u,0u};
    }
    issue(0);

    #pragma unroll 1
    for (int step = 0; step < 16; ++step) {            // K over ci, BK=32 (cig == step)
        __syncthreads();                               // prev compute done reading LDS
        #pragma unroll
        for (int k = 0; k < 4; ++k)
            lds[(k*4 + sg)*66 + sc] = st[k];           // waits on st loads (vmcnt)
        __syncthreads();
        if (step < 15) issue((step+1) * 4);            // loads fly under the 9-tap compute

        #pragma unroll
        for (int kh = 0; kh < 3; ++kh) {
            int rt = wn + kh;                           // row within 4-row tile
            #pragma unroll
            for (int kw = 0; kw < 3; ++kw) {
                int t = kh*3 + kw;
                short8 a[4], bx[4];
                #pragma unroll
                for (int nf = 0; nf < 4; ++nf) {        // B: x frags, single ds_read_b128 each
                    int slot = (rt*4 + lg)*66 + nf*16 + kw + l15;
                    bx[nf] = as_s8(lds[slot]);
                }
                #pragma unroll
                for (int mf = 0; mf < 4; ++mf)          // A: coalesced 1KB fragment reads (L2)
                    a[mf] = as_s8(wf4[((t*16 + step)*32 + cog0 + mf)*64 + lane]);
                #pragma unroll
                for (int mf = 0; mf < 4; ++mf)
                    #pragma unroll
                    for (int nf = 0; nf < 4; ++nf)
                        acc[mf][nf] = __builtin_amdgcn_mfma_f32_16x16x32_bf16(
                            a[mf], bx[nf], acc[mf][nf], 0, 0, 0);
            }
        }
    }

    // epilogue: scale by demod[b][co], write NCHW f32
    int r = r0 + wn;
    const float* dmp = demod + b*512;
    #pragma unroll
    for (int mf = 0; mf < 4; ++mf) {
        #pragma unroll
        for (int reg = 0; reg < 4; ++reg) {
            int co = cobase + mf*16 + lg*4 + reg;       // C/D: row=(lane>>4)*4+reg
            float dm = dmp[co];
            #pragma unroll
            for (int nf = 0; nf < 4; ++nf) {
                int c = nf*16 + l15;                    // C/D: col=lane&15
                out[((b*512 + co)*64 + r)*64 + c] = acc[mf][nf][reg] * dm;
            }
        }
    }
}

extern "C" void kernel_launch(void* const* d_in, const int* in_sizes, int n_in,
                              void* d_out, int out_size, void* d_ws, size_t ws_size,
                              hipStream_t stream) {
    const float* x      = (const float*)d_in[0];
    const float* style  = (const float*)d_in[1];
    const float* weight = (const float*)d_in[2];
    const float* mw     = (const float*)d_in[3];
    const float* mb     = (const float*)d_in[4];
    float* out = (float*)d_out;

    // workspace layout (38.3MB total):
    float* s_ws           = (float*)d_ws;                                  // 16KB
    float* demod_ws       = (float*)((char*)d_ws + 16384);                 // 16KB
    unsigned short* wfrag = (unsigned short*)((char*)d_ws + 32768);        // 4.5MB  [9][16][32][64][8] bf16
    unsigned short* xs    = (unsigned short*)((char*)d_ws + 4751360);      // 32MB   [8][64][64][512] bf16

    k_style<<<1024, 256, 0, stream>>>(style, mw, mb, s_ws, out + OUT_IMG);
    k_wprep<<<512, 256, 0, stream>>>(weight, wfrag);
    k_demod<<<512, 256, 0, stream>>>(weight, s_ws, demod_ws);
    k_xprep<<<dim3(2, 64, 8), 256, 0, stream>>>(x, s_ws, xs);
    k_conv<<<dim3(4, 32, 8), 256, 0, stream>>>(xs, wfrag, demod_ws, out);
}

// Round 5
// 272.108 us; speedup vs baseline: 2.5088x; 1.2996x over previous
//
#include <hip/hip_runtime.h>
#include <hip/hip_bf16.h>

// ModulatedConv2d: out = demod[b,co] * ( (conv_scale*weight) ⊛ (x * s[b,ci]) ), plus s5 output.
// Shared-filter implicit GEMM, bf16 MFMA 16x16x32, fp32 acc.
// R5: per-wave ILP attack. Wave tile 64co x 128pos (nf=8: 2 full output rows), block =
//     4 waves x 64co = 256co x 2rows. 288 MFMA per wave-step from 36 global A-loads
//     (halved latency exposure per MFMA) + 72 LDS reads. Single 16.9KB LDS tile + T14.

typedef __attribute__((ext_vector_type(8))) short short8;
typedef __attribute__((ext_vector_type(4))) float f32x4;

#define LIN_SCALE 0.04419417382415922f     /* 1/sqrt(512) */
#define CONV_SCALE 0.014731391274719739f   /* 1/sqrt(4608) */
#define CONV_SCALE2 (1.0f/4608.0f)
#define OUT_IMG (8*512*64*64)

static __device__ __forceinline__ unsigned short f2bf(float f) {
    union { float f; unsigned int u; } a; a.f = f;
    unsigned int u = a.u;
    return (unsigned short)((u + 0x7fffu + ((u >> 16) & 1u)) >> 16); // RNE
}
static __device__ __forceinline__ short8 as_s8(uint4 v) {
    union { uint4 u; short8 s; } x; x.u = v; return x.s;
}

// ---------------- kernel 1: s[b,ci] = style @ (mod_weight*lin_scale)^T + bias; also s5 out ----
__global__ __launch_bounds__(256) void k_style(const float* __restrict__ style,
                                               const float* __restrict__ mw,
                                               const float* __restrict__ mb,
                                               float* __restrict__ s_ws,
                                               float* __restrict__ out_s5) {
    int wid = blockIdx.x * 4 + (threadIdx.x >> 6);   // 4096 waves: one per (b,ci)
    int lane = threadIdx.x & 63;
    int b = wid >> 9, ci = wid & 511;
    float sum = 0.f;
    for (int k = lane; k < 512; k += 64)
        sum += style[b*512 + k] * mw[ci*512 + k];
    for (int off = 32; off > 0; off >>= 1) sum += __shfl_xor(sum, off);
    if (lane == 0) {
        float v = sum * LIN_SCALE + mb[ci];
        s_ws[b*512 + ci] = v;
        out_s5[b*512 + ci] = v;   // s5 flat = (B,1,Cin,1,1)
    }
}

// ------- kernel 2b: wfrag in MFMA A-fragment order: [t][cig(16)][cog(32)][lane(64)] x uint4 ---
// lane l holds 8 bf16: w[co = cog*16 + (l&15)][ci = cig*32 + (l>>4)*8 + j][t] * conv_scale
__global__ __launch_bounds__(256) void k_wprep(const float* __restrict__ weight,
                                               unsigned short* __restrict__ wfrag) {
    __shared__ float wsh[4608];
    int co = blockIdx.x;
    int cog = co >> 4, l15 = co & 15;
    for (int i = threadIdx.x; i < 4608; i += 256) wsh[i] = weight[co*4608 + i];
    __syncthreads();
    uint4* wf4 = (uint4*)wfrag;
    for (int idx = threadIdx.x; idx < 576; idx += 256) {   // 9 t x 16 cig x 4 lg
        int t = idx / 64;
        int rem = idx & 63;
        int cig = rem >> 2, lg = rem & 3;
        union { unsigned short h[8]; uint4 v; } u;
        #pragma unroll
        for (int j = 0; j < 8; ++j)
            u.h[j] = f2bf(wsh[(cig*32 + lg*8 + j)*9 + t] * CONV_SCALE);
        wf4[((t*16 + cig)*32 + cog)*64 + lg*16 + l15] = u.v;
    }
}

// ---------------- kernel 2: demod[b][co] = rsqrt(conv_scale^2 * sum((w*s)^2) + eps) ----------
__global__ __launch_bounds__(256) void k_demod(const float* __restrict__ weight,
                                               const float* __restrict__ s_ws,
                                               float* __restrict__ demod) {
    __shared__ float s2[4096];
    __shared__ float red[4][8];
    int co = blockIdx.x;
    for (int i = threadIdx.x; i < 4096; i += 256) { float v = s_ws[i]; s2[i] = v*v; }
    __syncthreads();
    float acc[8] = {0,0,0,0,0,0,0,0};
    for (int idx = threadIdx.x; idx < 4608; idx += 256) {
        float w = weight[co*4608 + idx];
        float w2 = w*w;
        int ci = idx / 9;
        #pragma unroll
        for (int b = 0; b < 8; ++b) acc[b] += w2 * s2[b*512 + ci];
    }
    int lane = threadIdx.x & 63, wv = threadIdx.x >> 6;
    #pragma unroll
    for (int b = 0; b < 8; ++b) {
        float v = acc[b];
        for (int off = 32; off > 0; off >>= 1) v += __shfl_xor(v, off);
        if (lane == 0) red[wv][b] = v;
    }
    __syncthreads();
    if (threadIdx.x < 8) {
        float t = red[0][threadIdx.x] + red[1][threadIdx.x]
                + red[2][threadIdx.x] + red[3][threadIdx.x];
        demod[threadIdx.x*512 + co] = rsqrtf(t * CONV_SCALE2 + 1e-8f);
    }
}

// ---------------- kernel 3: xs[b][h][w][ci] = bf16(x[b][ci][h][w] * s[b][ci])  (NHWC) --------
__global__ __launch_bounds__(256) void k_xprep(const float* __restrict__ x,
                                               const float* __restrict__ s_ws,
                                               unsigned short* __restrict__ xs) {
    __shared__ unsigned short tile[32 * 520];        // 32 w-rows x 512 ci, stride 520
    int w0 = blockIdx.x * 32, h = blockIdx.y, b = blockIdx.z;
    int t = threadIdx.x;
    int wl = t & 31, cih = t >> 5;                    // 32 w x 8 ci per iter
    for (int ci0 = 0; ci0 < 512; ci0 += 8) {
        int ci = ci0 + cih;
        float sv = s_ws[b*512 + ci];
        float v = x[((b*512 + ci)*64 + h)*64 + (w0 + wl)] * sv;   // coalesced over w
        tile[wl*520 + ci] = f2bf(v);
    }
    __syncthreads();
    int lane = t & 63, wv = t >> 6;
    const uint4* t4 = (const uint4*)tile;             // 65 uint4 per row
    uint4* xs4 = (uint4*)xs;
    for (int w = wv; w < 32; w += 4) {
        uint4 v = t4[w*65 + lane];
        xs4[((b*64 + h)*64 + (w0 + w))*64 + lane] = v;  // coalesced 1KB row store
    }
}

// ---------------- kernel 4: implicit-GEMM conv, epilogue demod scale -------------------------
// Block: 256co x (2 rows x 64 cols). 4 waves stacked in co; wave tile 64co x 128pos
// (nf=8: nf>>2 selects output row, nf&3 selects 16-col group). mf=4.
// LDS x-tile [4 rows][4 ci-grps][66 cols][8ci] = 16.9KB single buffer; T14 pipeline.
__global__ __launch_bounds__(256, 2) void k_conv(const unsigned short* __restrict__ xs,
                                                 const unsigned short* __restrict__ wfrag,
                                                 const float* __restrict__ demod,
                                                 float* __restrict__ out) {
    __shared__ uint4 lds[1056];                       // [r*4+g][66] uint4
    int cot = blockIdx.x;                             // 0..1  -> co0 = 256*cot
    int r0  = blockIdx.y * 2;                         // 0..62
    int b   = blockIdx.z;
    int tid = threadIdx.x;
    int lane = tid & 63, wid = tid >> 6;
    int l15 = lane & 15, lg = lane >> 4;
    int cobase = cot*256 + wid*64;
    int cog0 = cobase >> 4;                           // base co-group (16-co units)

    const uint4* xs4 = (const uint4*)xs;
    const uint4* wf4 = (const uint4*)wfrag;

    f32x4 acc[4][8];
    #pragma unroll
    for (int i = 0; i < 4; ++i)
        #pragma unroll
        for (int j = 0; j < 8; ++j) acc[i][j] = (f32x4){0.f,0.f,0.f,0.f};

    // staging: interior cols only (c=1..64), 4 rows x 4 grps x 64 cols = 1024 = 4/thread
    int sg  = tid & 3;                                // ci-grp
    int sc  = 1 + (tid >> 2);                         // tile col 1..64
    int scm1 = tid >> 2;                              // spatial col 0..63
    const uint4* xrow = xs4 + ((b*64 + (r0 - 1))*64 + scm1)*64 + sg;  // row k adds k*4096

    uint4 st[4];
    auto issue = [&](int cq) {
        #pragma unroll
        for (int k = 0; k < 4; ++k) {
            int rin = r0 - 1 + k;
            st[k] = (uint4){0u,0u,0u,0u};
            if ((unsigned)rin < 64u) st[k] = xrow[k*4096 + cq];
        }
    };

    // halo cols c=0 and c=65 are structurally zero (W padding) for every step: zero once.
    if (tid < 32) {
        int q = tid & 15;                              // r*4+g
        int col = (tid >> 4) ? 65 : 0;
        lds[q*66 + col] = (uint4){0u,0u,0u,0u};
    }
    issue(0);

    #pragma unroll 1
    for (int step = 0; step < 16; ++step) {            // K over ci, BK=32 (cig == step)
        __syncthreads();                               // prev compute done reading LDS
        #pragma unroll
        for (int k = 0; k < 4; ++k)
            lds[(k*4 + sg)*66 + sc] = st[k];           // waits on st loads (vmcnt)
        __syncthreads();
        if (step < 15) issue((step+1) * 4);            // loads fly under the 9-tap compute

        #pragma unroll
        for (int kh = 0; kh < 3; ++kh) {
            #pragma unroll
            for (int kw = 0; kw < 3; ++kw) {
                int t = kh*3 + kw;
                short8 a[4], bx[8];
                #pragma unroll
                for (int nf = 0; nf < 8; ++nf) {        // B: x frags, single ds_read_b128 each
                    int rt = (nf >> 2) + kh;            // input row within 4-row tile
                    int slot = (rt*4 + lg)*66 + (nf & 3)*16 + kw + l15;
                    bx[nf] = as_s8(lds[slot]);
                }
                #pragma unroll
                for (int mf = 0; mf < 4; ++mf)          // A: coalesced 1KB fragment reads (L2)
                    a[mf] = as_s8(wf4[((t*16 + step)*32 + cog0 + mf)*64 + lane]);
                #pragma unroll
                for (int mf = 0; mf < 4; ++mf)
                    #pragma unroll
                    for (int nf = 0; nf < 8; ++nf)
                        acc[mf][nf] = __builtin_amdgcn_mfma_f32_16x16x32_bf16(
                            a[mf], bx[nf], acc[mf][nf], 0, 0, 0);
            }
        }
    }

    // epilogue: scale by demod[b][co], write NCHW f32
    const float* dmp = demod + b*512;
    #pragma unroll
    for (int mf = 0; mf < 4; ++mf) {
        #pragma unroll
        for (int reg = 0; reg < 4; ++reg) {
            int co = cobase + mf*16 + lg*4 + reg;       // C/D: row=(lane>>4)*4+reg
            float dm = dmp[co];
            #pragma unroll
            for (int nf = 0; nf < 8; ++nf) {
                int r = r0 + (nf >> 2);
                int c = (nf & 3)*16 + l15;              // C/D: col=lane&15
                out[((b*512 + co)*64 + r)*64 + c] = acc[mf][nf][reg] * dm;
            }
        }
    }
}

extern "C" void kernel_launch(void* const* d_in, const int* in_sizes, int n_in,
                              void* d_out, int out_size, void* d_ws, size_t ws_size,
                              hipStream_t stream) {
    const float* x      = (const float*)d_in[0];
    const float* style  = (const float*)d_in[1];
    const float* weight = (const float*)d_in[2];
    const float* mw     = (const float*)d_in[3];
    const float* mb     = (const float*)d_in[4];
    float* out = (float*)d_out;

    // workspace layout (38.3MB total):
    float* s_ws           = (float*)d_ws;                                  // 16KB
    float* demod_ws       = (float*)((char*)d_ws + 16384);                 // 16KB
    unsigned short* wfrag = (unsigned short*)((char*)d_ws + 32768);        // 4.5MB  [9][16][32][64][8] bf16
    unsigned short* xs    = (unsigned short*)((char*)d_ws + 4751360);      // 32MB   [8][64][64][512] bf16

    k_style<<<1024, 256, 0, stream>>>(style, mw, mb, s_ws, out + OUT_IMG);
    k_wprep<<<512, 256, 0, stream>>>(weight, wfrag);
    k_demod<<<512, 256, 0, stream>>>(weight, s_ws, demod_ws);
    k_xprep<<<dim3(2, 64, 8), 256, 0, stream>>>(x, s_ws, xs);
    k_conv<<<dim3(2, 32, 8), 256, 0, stream>>>(xs, wfrag, demod_ws, out);
}